// Round 1
// baseline (2828.482 us; speedup 1.0000x reference)
//
#include <hip/hip_runtime.h>
#include <hip/hip_bf16.h>

#define B_ 64
#define S_ 512
#define D_ 256
#define H_ 512

typedef __attribute__((ext_vector_type(8))) short bf16x8;
typedef __attribute__((ext_vector_type(4))) float f32x4;
typedef __attribute__((ext_vector_type(4))) unsigned int uint4v;
typedef unsigned short ushort_t;
typedef unsigned long long u64_t;

__device__ __forceinline__ ushort_t f2bf(float f) {
    __hip_bfloat16 h = __float2bfloat16(f);   // RNE rounding
    return *reinterpret_cast<ushort_t*>(&h);
}
__device__ __forceinline__ float sigmoid_f(float x) { return 1.f / (1.f + __expf(-x)); }
__device__ __forceinline__ float tanh_f(float x) { return 1.f - 2.f / (__expf(2.f * x) + 1.f); }

__device__ __forceinline__ void lds_barrier() {
    asm volatile("s_waitcnt lgkmcnt(0)\n\ts_barrier" ::: "memory");
}

// R11: tag-fused h exchange.
//  * Old protocol serialized per step: h-store + vmcnt(0) drain -> flag store
//    -> 64-wave poll storm on 2 cache lines -> separate h-data RT. The storm
//    queued the flag stores behind poll reads (theory for the 4x inflation
//    over the latency-sum estimate).
//  * New protocol: each h entry is an aligned u64 {tag(t) in hi dword |
//    2xbf16 data in lo dword}, written by ONE relaxed agent atomic store
//    (64-bit single-copy atomic: tag and data are inseparable). Consumers
//    retry-load 8 entries/thread (relaxed agent atomic loads = the R7-proven
//    coherent read idiom) until all tags == t. No drain, no flags, no
//    separate detect RT; poll traffic spread over 256 lines/group-step.
//  * 2 hbuf slots are sufficient: storing h(t+2) requires having read all of
//    h(t+1), which required every producer wave to have finished reading
//    h(t) (double-buffer causality at wave granularity).
//  * XCD ranking dropped: agent atomics are XCD-agnostic -> direct blockIdx
//    mapping, grid = 32 blocks.
//  * x scheduling kept from R10: x(t+1) register-prefetch issued right after
//    the poll breaks (not before: retry waitcnts would wait on HBM x loads),
//    consumed in G for the xS(t+1) LDS write.
__global__ __launch_bounds__(512, 2) void lstm_rec(
    const float* __restrict__ X,
    const float* __restrict__ Wf, const float* __restrict__ Wi,
    const float* __restrict__ Wo, const float* __restrict__ Wc,
    const float* __restrict__ bfp, const float* __restrict__ bip,
    const float* __restrict__ bop, const float* __restrict__ bcp,
    const float* __restrict__ Uf, const float* __restrict__ Ui,
    const float* __restrict__ Uo, const float* __restrict__ Uc,
    const float* __restrict__ Wfc,
    float* __restrict__ pred, u64_t* __restrict__ hbuf,
    float* __restrict__ outH, float* __restrict__ outC)
{
    __shared__ ushort_t hS[16 * 520];
    __shared__ ushort_t xS[16 * 264];
    __shared__ float gact[4][16][68];

    const int tid  = threadIdx.x;
    const int w    = tid >> 6;
    const int lane = tid & 63;
    const int q    = lane >> 4;
    const int m    = lane & 15;
    const int gate = w >> 1;
    const int half = w & 1;

    // direct block -> (group, slice) mapping; grid is exactly 32 blocks
    const int g = blockIdx.x >> 3;   // batch rows g*16 .. +15
    const int s = blockIdx.x & 7;    // h cols  s*64 .. +63

    const int ncol0 = s * 64 + half * 32 + m;
    const int ncol1 = ncol0 + 16;

    const float* Ug = (gate == 0) ? Uf : (gate == 1) ? Ui : (gate == 2) ? Uo : Uc;
    const float* Wg = (gate == 0) ? Wf : (gate == 1) ? Wi : (gate == 2) ? Wo : Wc;
    const float* bg = (gate == 0) ? bfp : (gate == 1) ? bip : (gate == 2) ? bop : bcp;

    const float bias0 = bg[ncol0];
    const float bias1 = bg[ncol1];

    // ---- one-time: B-fragments into registers (fp32 -> bf16 RNE) ----
    bf16x8 UF[2][16];
    bf16x8 WF[2][8];
    #pragma unroll
    for (int tt = 0; tt < 2; ++tt) {
        const int nc = tt ? ncol1 : ncol0;
        #pragma unroll
        for (int ks = 0; ks < 16; ++ks) {
            bf16x8 v;
            #pragma unroll
            for (int j = 0; j < 8; ++j)
                v[j] = (short)f2bf(Ug[(ks * 32 + q * 8 + j) * H_ + nc]);
            UF[tt][ks] = v;
        }
        #pragma unroll
        for (int ks = 0; ks < 8; ++ks) {
            bf16x8 v;
            #pragma unroll
            for (int j = 0; j < 8; ++j)
                v[j] = (short)f2bf(Wg[(ks * 32 + q * 8 + j) * H_ + nc]);
            WF[tt][ks] = v;
        }
    }

    const int urow  = tid >> 5;
    const int upair = tid & 31;
    const float2 wfc2 = *(const float2*)&Wfc[s * 64 + 2 * upair];

    float cr0 = 0.f, cr1 = 0.f;

    // ---- preamble: stage x(0) into LDS ----
    {
        const float* xsrc = &X[((size_t)(g * 16 + urow) * S_ + 0) * D_ + upair * 8];
        float4 a = *(const float4*)xsrc;
        float4 b = *(const float4*)(xsrc + 4);
        bf16x8 v;
        v[0] = (short)f2bf(a.x); v[1] = (short)f2bf(a.y);
        v[2] = (short)f2bf(a.z); v[3] = (short)f2bf(a.w);
        v[4] = (short)f2bf(b.x); v[5] = (short)f2bf(b.y);
        v[6] = (short)f2bf(b.z); v[7] = (short)f2bf(b.w);
        *(bf16x8*)&xS[urow * 264 + upair * 8] = v;
    }

    float4 xr0, xr1;

    for (int t = 0; t < S_; ++t) {
        // ---- C: fused poll+load of h(t); entry = {tag | 2xbf16}. slot t&1.
        //      t=0 hits the memset: tag 0 == t, data 0 == h(0). ----
        {
            const int pr = upair * 8;     // first of 8 consecutive col-pairs
            u64_t* pe = hbuf + ((size_t)((t & 1) * B_ + g * 16 + urow) * 256 + pr);
            const unsigned int tg = (unsigned int)t;
            u64_t e0, e1, e2, e3, e4, e5, e6, e7;
            for (;;) {
                e0 = __hip_atomic_load(pe + 0, __ATOMIC_RELAXED, __HIP_MEMORY_SCOPE_AGENT);
                e1 = __hip_atomic_load(pe + 1, __ATOMIC_RELAXED, __HIP_MEMORY_SCOPE_AGENT);
                e2 = __hip_atomic_load(pe + 2, __ATOMIC_RELAXED, __HIP_MEMORY_SCOPE_AGENT);
                e3 = __hip_atomic_load(pe + 3, __ATOMIC_RELAXED, __HIP_MEMORY_SCOPE_AGENT);
                e4 = __hip_atomic_load(pe + 4, __ATOMIC_RELAXED, __HIP_MEMORY_SCOPE_AGENT);
                e5 = __hip_atomic_load(pe + 5, __ATOMIC_RELAXED, __HIP_MEMORY_SCOPE_AGENT);
                e6 = __hip_atomic_load(pe + 6, __ATOMIC_RELAXED, __HIP_MEMORY_SCOPE_AGENT);
                e7 = __hip_atomic_load(pe + 7, __ATOMIC_RELAXED, __HIP_MEMORY_SCOPE_AGENT);
                bool ok = (unsigned int)(e0 >> 32) == tg && (unsigned int)(e1 >> 32) == tg
                       && (unsigned int)(e2 >> 32) == tg && (unsigned int)(e3 >> 32) == tg
                       && (unsigned int)(e4 >> 32) == tg && (unsigned int)(e5 >> 32) == tg
                       && (unsigned int)(e6 >> 32) == tg && (unsigned int)(e7 >> 32) == tg;
                if (__ballot(ok) == ~0ull) break;
            }
            // x(t+1) register prefetch: issued only after the poll breaks so
            // retry waitcnts never wait on HBM; consumed in G (~1 phase later)
            if (t + 1 < S_) {
                const float* xsrc = &X[((size_t)(g * 16 + urow) * S_ + (t + 1)) * D_ + upair * 8];
                xr0 = *(const float4*)xsrc;
                xr1 = *(const float4*)(xsrc + 4);
            }
            uint4v ra, rb;
            ra[0] = (unsigned int)e0; ra[1] = (unsigned int)e1;
            ra[2] = (unsigned int)e2; ra[3] = (unsigned int)e3;
            rb[0] = (unsigned int)e4; rb[1] = (unsigned int)e5;
            rb[2] = (unsigned int)e6; rb[3] = (unsigned int)e7;
            *(uint4v*)&hS[urow * 520 + pr * 2]     = ra;
            *(uint4v*)&hS[urow * 520 + pr * 2 + 8] = rb;
        }
        lds_barrier();   // D

        // ---- E: gate GEMMs + activations ----
        f32x4 accA0 = {bias0, bias0, bias0, bias0};
        f32x4 accA1 = {bias1, bias1, bias1, bias1};
        f32x4 accB0 = {0.f, 0.f, 0.f, 0.f};
        f32x4 accB1 = {0.f, 0.f, 0.f, 0.f};
        #pragma unroll
        for (int ks = 0; ks < 8; ++ks) {
            bf16x8 a = *(const bf16x8*)&xS[m * 264 + ks * 32 + q * 8];
            accA0 = __builtin_amdgcn_mfma_f32_16x16x32_bf16(a, WF[0][ks], accA0, 0, 0, 0);
            accA1 = __builtin_amdgcn_mfma_f32_16x16x32_bf16(a, WF[1][ks], accA1, 0, 0, 0);
        }
        #pragma unroll
        for (int ks = 0; ks < 16; ++ks) {
            bf16x8 a = *(const bf16x8*)&hS[m * 520 + ks * 32 + q * 8];
            accB0 = __builtin_amdgcn_mfma_f32_16x16x32_bf16(a, UF[0][ks], accB0, 0, 0, 0);
            accB1 = __builtin_amdgcn_mfma_f32_16x16x32_bf16(a, UF[1][ks], accB1, 0, 0, 0);
        }
        #pragma unroll
        for (int j = 0; j < 4; ++j) {
            float v0 = accA0[j] + accB0[j];
            float v1 = accA1[j] + accB1[j];
            v0 = (gate < 3) ? sigmoid_f(v0) : tanh_f(v0);
            v1 = (gate < 3) ? sigmoid_f(v1) : tanh_f(v1);
            gact[gate][q * 4 + j][half * 32 + m]      = v0;
            gact[gate][q * 4 + j][half * 32 + 16 + m] = v1;
        }
        lds_barrier();   // F

        // ---- G: update; single fused {tag|data} store, fire-and-forget ----
        float2 f2v = *(const float2*)&gact[0][urow][2 * upair];
        float2 i2v = *(const float2*)&gact[1][urow][2 * upair];
        float2 o2v = *(const float2*)&gact[2][urow][2 * upair];
        float2 ch2 = *(const float2*)&gact[3][urow][2 * upair];
        cr0 = f2v.x * cr0 + i2v.x * ch2.x;
        cr1 = f2v.y * cr1 + i2v.y * ch2.y;
        float hv0 = o2v.x * tanh_f(cr0);
        float hv1 = o2v.y * tanh_f(cr1);

        if (t < S_ - 1) {
            unsigned int packed = (unsigned int)f2bf(hv0) | ((unsigned int)f2bf(hv1) << 16);
            u64_t ent = ((u64_t)(unsigned int)(t + 1) << 32) | (u64_t)packed;
            u64_t* hdst = hbuf + ((size_t)(((t + 1) & 1) * B_ + g * 16 + urow) * 256
                                  + s * 32 + upair);
            __hip_atomic_store(hdst, ent, __ATOMIC_RELAXED, __HIP_MEMORY_SCOPE_AGENT);
            // xS(t+1): f2bf VALU work overlaps the in-flight h-entry store
            bf16x8 v;
            v[0] = (short)f2bf(xr0.x); v[1] = (short)f2bf(xr0.y);
            v[2] = (short)f2bf(xr0.z); v[3] = (short)f2bf(xr0.w);
            v[4] = (short)f2bf(xr1.x); v[5] = (short)f2bf(xr1.y);
            v[6] = (short)f2bf(xr1.z); v[7] = (short)f2bf(xr1.w);
            *(bf16x8*)&xS[urow * 264 + upair * 8] = v;
        } else {
            *(float2*)&outH[(g * 16 + urow) * H_ + s * 64 + 2 * upair] = make_float2(hv0, hv1);
            *(float2*)&outC[(g * 16 + urow) * H_ + s * 64 + 2 * upair] = make_float2(cr0, cr1);
        }

        // ---- pred head (off the inter-block critical path) ----
        float pv = hv0 * wfc2.x + hv1 * wfc2.y;
        pv += __shfl_xor(pv, 16);
        pv += __shfl_xor(pv, 8);
        pv += __shfl_xor(pv, 4);
        pv += __shfl_xor(pv, 2);
        pv += __shfl_xor(pv, 1);
        if (upair == 0) atomicAdd(&pred[(g * 16 + urow) * S_ + t], pv);
    }
}

__global__ void pred_fin(const float* __restrict__ pred,
                         const float* __restrict__ bfc,
                         float* __restrict__ out)
{
    int i = blockIdx.x * blockDim.x + threadIdx.x;
    if (i < B_ * S_) out[i] = pred[i] + bfc[0];
}

extern "C" void kernel_launch(void* const* d_in, const int* in_sizes, int n_in,
                              void* d_out, int out_size, void* d_ws, size_t ws_size,
                              hipStream_t stream) {
    const float* X   = (const float*)d_in[0];
    const float* Wf  = (const float*)d_in[1];
    const float* Wi  = (const float*)d_in[2];
    const float* Wo  = (const float*)d_in[3];
    const float* Wc  = (const float*)d_in[4];
    const float* bfp = (const float*)d_in[5];
    const float* bip = (const float*)d_in[6];
    const float* bop = (const float*)d_in[7];
    const float* bcp = (const float*)d_in[8];
    const float* Uf  = (const float*)d_in[9];
    const float* Ui  = (const float*)d_in[10];
    const float* Uo  = (const float*)d_in[11];
    const float* Uc  = (const float*)d_in[12];
    const float* Wfc = (const float*)d_in[13];
    const float* bfc = (const float*)d_in[14];

    // ws layout: pred fp32 [64][512] @0 (128KB)
    //            | hbuf u64 [2][64][256] @131072 (256KB) -> ends 393216
    float*        pred = (float*)d_ws;
    u64_t*        hbuf = (u64_t*)((char*)d_ws + 131072);

    hipMemsetAsync(d_ws, 0, 131072 + 262144, stream);   // pred + hbuf (tags=0)

    float* out = (float*)d_out;
    lstm_rec<<<32, 512, 0, stream>>>(X, Wf, Wi, Wo, Wc, bfp, bip, bop, bcp,
                                     Uf, Ui, Uo, Uc, Wfc,
                                     pred, hbuf,
                                     out + 32768, out + 65536);
    pred_fin<<<128, 256, 0, stream>>>(pred, bfc, out);
}

// Round 2
// 2230.947 us; speedup vs baseline: 1.2678x; 1.2678x over previous
//
#include <hip/hip_runtime.h>
#include <hip/hip_bf16.h>

#define B_ 64
#define S_ 512
#define D_ 256
#define H_ 512

typedef __attribute__((ext_vector_type(8))) short bf16x8;
typedef __attribute__((ext_vector_type(4))) float f32x4;
typedef __attribute__((ext_vector_type(4))) unsigned int uint4v;
typedef unsigned short ushort_t;
typedef unsigned long long u64_t;

__device__ __forceinline__ ushort_t f2bf(float f) {
    __hip_bfloat16 h = __float2bfloat16(f);   // RNE rounding
    return *reinterpret_cast<ushort_t*>(&h);
}
__device__ __forceinline__ float sigmoid_f(float x) { return 1.f / (1.f + __expf(-x)); }
__device__ __forceinline__ float tanh_f(float x) { return 1.f - 2.f / (__expf(2.f * x) + 1.f); }

__device__ __forceinline__ void lds_barrier() {
    asm volatile("s_waitcnt lgkmcnt(0)\n\ts_barrier" ::: "memory");
}

// R12: fused tag+data exchange, KEPT IN XCD-LOCAL L2.
//  * R11 post-mortem: agent-atomic loads/stores bypass L2 (FETCH_SIZE 45->400MB)
//    — the whole data plane moved to L3 latency and the no-backoff retry loop
//    stormed it. R12 keeps the R11 single-store protocol but restores the
//    R9/R10 L2 locality:
//  * entry = aligned u64 {tag(t) hi | 2xbf16 lo}; producer writes it with ONE
//    plain global_store_dwordx2 sc0 sc1 (write-through: updates local L2 AND
//    forwards to L3; R7-proven mixed encoding). Fire-and-forget: no vmcnt
//    drain, no flag store.
//  * consumer fast path (uniform group, same XCD): plain sc0 dwordx4 loads —
//    L2-local, fresh by capacity (>48KB flows through L1 between slot
//    reuses); tag==t check per entry. On any mismatch -> escalate to
//    agent-atomic u64 loads with s_sleep(1) backoff (correct via L3 since the
//    store wrote through). Never re-probe sc0 after a miss: a failed probe
//    pollutes L1 with the stale line; the atomic's own returned {tag|data}
//    is authoritative, so L1-stale-spin is structurally impossible.
//  * 2 hbuf slots: storing h(t+2) requires having read all of h(t+1), which
//    required every block to have finished reading h(t).
//  * XCD self-ranking (R9) kept: groups of 8 blocks co-located per XCD;
//    non-uniform groups (rare) skip the sc0 probe and go straight to the
//    atomic path.
//  * x scheduling (R10) kept: x(t+1) prefetch issued after the poll resolves,
//    consumed in G for the xS(t+1) write.
__global__ __launch_bounds__(512, 2) void lstm_rec(
    const float* __restrict__ X,
    const float* __restrict__ Wf, const float* __restrict__ Wi,
    const float* __restrict__ Wo, const float* __restrict__ Wc,
    const float* __restrict__ bfp, const float* __restrict__ bip,
    const float* __restrict__ bop, const float* __restrict__ bcp,
    const float* __restrict__ Uf, const float* __restrict__ Ui,
    const float* __restrict__ Uo, const float* __restrict__ Uc,
    const float* __restrict__ Wfc,
    float* __restrict__ pred, u64_t* __restrict__ hbuf,
    unsigned int* __restrict__ xcdtab,
    float* __restrict__ outH, float* __restrict__ outC)
{
    __shared__ ushort_t hS[16 * 520];
    __shared__ ushort_t xS[16 * 264];
    __shared__ float gact[4][16][68];
    __shared__ int meta[2];   // [0]=rank, [1]=uniform

    const int tid  = threadIdx.x;
    const int w    = tid >> 6;
    const int lane = tid & 63;
    const int q    = lane >> 4;
    const int m    = lane & 15;
    const int gate = w >> 1;
    const int half = w & 1;

    // ---- XCD self-assignment: wave 0 computes, LDS-broadcasts (R9-proven) ----
    if (w == 0) {
        unsigned int xcd;
        asm volatile("s_getreg_b32 %0, hwreg(HW_REG_XCC_ID)" : "=s"(xcd));
        xcd &= 15u;
        if (lane == 0)
            __hip_atomic_store(&xcdtab[blockIdx.x], xcd + 1u,
                               __ATOMIC_RELEASE, __HIP_MEMORY_SCOPE_AGENT);
        unsigned int entry;
        for (;;) {
            entry = __hip_atomic_load(&xcdtab[lane], __ATOMIC_ACQUIRE, __HIP_MEMORY_SCOPE_AGENT);
            if (__ballot(entry != 0u) == ~0ull) break;
            __builtin_amdgcn_s_sleep(1);
        }
        const unsigned int xcd_j = entry - 1u;
        const unsigned int key_j = (xcd_j << 8) | (unsigned int)lane;
        const unsigned int mykey = (xcd << 8) | (unsigned int)blockIdx.x;
        const int rank = __popcll(__ballot(key_j < mykey));
        const int c_lt = __popcll(__ballot(xcd_j < xcd));
        const int c_eq = __popcll(__ballot(xcd_j == xcd));
        const int gg   = rank >> 3;
        const bool uni = (c_lt <= gg * 8) && (gg * 8 + 8 <= c_lt + c_eq);
        if (lane == 0) { meta[0] = rank; meta[1] = uni ? 1 : 0; }
    }
    __syncthreads();
    const int  rank    = meta[0];
    const bool uniform = meta[1] != 0;
    if (rank >= 32) return;
    const int g = rank >> 3;
    const int s = rank & 7;

    const int ncol0 = s * 64 + half * 32 + m;
    const int ncol1 = ncol0 + 16;

    const float* Ug = (gate == 0) ? Uf : (gate == 1) ? Ui : (gate == 2) ? Uo : Uc;
    const float* Wg = (gate == 0) ? Wf : (gate == 1) ? Wi : (gate == 2) ? Wo : Wc;
    const float* bg = (gate == 0) ? bfp : (gate == 1) ? bip : (gate == 2) ? bop : bcp;

    const float bias0 = bg[ncol0];
    const float bias1 = bg[ncol1];

    // ---- one-time: B-fragments into registers (fp32 -> bf16 RNE) ----
    bf16x8 UF[2][16];
    bf16x8 WF[2][8];
    #pragma unroll
    for (int tt = 0; tt < 2; ++tt) {
        const int nc = tt ? ncol1 : ncol0;
        #pragma unroll
        for (int ks = 0; ks < 16; ++ks) {
            bf16x8 v;
            #pragma unroll
            for (int j = 0; j < 8; ++j)
                v[j] = (short)f2bf(Ug[(ks * 32 + q * 8 + j) * H_ + nc]);
            UF[tt][ks] = v;
        }
        #pragma unroll
        for (int ks = 0; ks < 8; ++ks) {
            bf16x8 v;
            #pragma unroll
            for (int j = 0; j < 8; ++j)
                v[j] = (short)f2bf(Wg[(ks * 32 + q * 8 + j) * H_ + nc]);
            WF[tt][ks] = v;
        }
    }

    const int urow  = tid >> 5;
    const int upair = tid & 31;
    const float2 wfc2 = *(const float2*)&Wfc[s * 64 + 2 * upair];

    float cr0 = 0.f, cr1 = 0.f;

    // ---- preamble: stage x(0) into LDS ----
    {
        const float* xsrc = &X[((size_t)(g * 16 + urow) * S_ + 0) * D_ + upair * 8];
        float4 a = *(const float4*)xsrc;
        float4 b = *(const float4*)(xsrc + 4);
        bf16x8 v;
        v[0] = (short)f2bf(a.x); v[1] = (short)f2bf(a.y);
        v[2] = (short)f2bf(a.z); v[3] = (short)f2bf(a.w);
        v[4] = (short)f2bf(b.x); v[5] = (short)f2bf(b.y);
        v[6] = (short)f2bf(b.z); v[7] = (short)f2bf(b.w);
        *(bf16x8*)&xS[urow * 264 + upair * 8] = v;
    }

    float4 xr0, xr1;

    for (int t = 0; t < S_; ++t) {
        // ---- C: fused poll+load of h(t); entry={tag|2xbf16}, slot t&1.
        //      t=0 hits the memset: tag 0 == t, data 0 == h(0). ----
        {
            const int row = tid >> 5;
            const int pr  = (tid & 31) * 8;    // 8 consecutive u64 entries (64B)
            u64_t* pe = hbuf + ((size_t)((t & 1) * B_ + g * 16 + row) * 256 + pr);
            const unsigned int tg = (unsigned int)t;
            uint4v ra, rb;                     // lo dwords (2xbf16 each)
            bool got = false;
            if (uniform) {
                // fast probe: sc0 (L1-allowed, L2-coherent within XCD)
                uint4v r0, r1, r2, r3;
                asm volatile(
                    "global_load_dwordx4 %0, %4, off sc0\n\t"
                    "global_load_dwordx4 %1, %5, off sc0\n\t"
                    "global_load_dwordx4 %2, %6, off sc0\n\t"
                    "global_load_dwordx4 %3, %7, off sc0\n\t"
                    "s_waitcnt vmcnt(0)"
                    : "=v"(r0), "=v"(r1), "=v"(r2), "=v"(r3)
                    : "v"(pe), "v"(pe + 2), "v"(pe + 4), "v"(pe + 6)
                    : "memory");
                bool ok = r0[1] == tg && r0[3] == tg && r1[1] == tg && r1[3] == tg
                       && r2[1] == tg && r2[3] == tg && r3[1] == tg && r3[3] == tg;
                if (__ballot(ok) == ~0ull) {
                    ra[0] = r0[0]; ra[1] = r0[2]; ra[2] = r1[0]; ra[3] = r1[2];
                    rb[0] = r2[0]; rb[1] = r2[2]; rb[2] = r3[0]; rb[3] = r3[2];
                    got = true;
                }
            }
            if (!got) {
                // escalation: agent-atomic u64 loads (L2-bypass, L3-fresh),
                // s_sleep backoff between rounds. Data+tag travel together,
                // so whichever load sees tag==t carries h(t).
                for (;;) {
                    u64_t e0 = __hip_atomic_load(pe + 0, __ATOMIC_RELAXED, __HIP_MEMORY_SCOPE_AGENT);
                    u64_t e1 = __hip_atomic_load(pe + 1, __ATOMIC_RELAXED, __HIP_MEMORY_SCOPE_AGENT);
                    u64_t e2 = __hip_atomic_load(pe + 2, __ATOMIC_RELAXED, __HIP_MEMORY_SCOPE_AGENT);
                    u64_t e3 = __hip_atomic_load(pe + 3, __ATOMIC_RELAXED, __HIP_MEMORY_SCOPE_AGENT);
                    u64_t e4 = __hip_atomic_load(pe + 4, __ATOMIC_RELAXED, __HIP_MEMORY_SCOPE_AGENT);
                    u64_t e5 = __hip_atomic_load(pe + 5, __ATOMIC_RELAXED, __HIP_MEMORY_SCOPE_AGENT);
                    u64_t e6 = __hip_atomic_load(pe + 6, __ATOMIC_RELAXED, __HIP_MEMORY_SCOPE_AGENT);
                    u64_t e7 = __hip_atomic_load(pe + 7, __ATOMIC_RELAXED, __HIP_MEMORY_SCOPE_AGENT);
                    bool ok = (unsigned int)(e0 >> 32) == tg && (unsigned int)(e1 >> 32) == tg
                           && (unsigned int)(e2 >> 32) == tg && (unsigned int)(e3 >> 32) == tg
                           && (unsigned int)(e4 >> 32) == tg && (unsigned int)(e5 >> 32) == tg
                           && (unsigned int)(e6 >> 32) == tg && (unsigned int)(e7 >> 32) == tg;
                    if (__ballot(ok) == ~0ull) {
                        ra[0] = (unsigned int)e0; ra[1] = (unsigned int)e1;
                        ra[2] = (unsigned int)e2; ra[3] = (unsigned int)e3;
                        rb[0] = (unsigned int)e4; rb[1] = (unsigned int)e5;
                        rb[2] = (unsigned int)e6; rb[3] = (unsigned int)e7;
                        break;
                    }
                    __builtin_amdgcn_s_sleep(1);
                }
            }
            // x(t+1) register prefetch: issued after the poll resolves so the
            // poll waitcnts never wait on HBM; consumed in G (~1 phase later)
            if (t + 1 < S_) {
                const float* xsrc = &X[((size_t)(g * 16 + urow) * S_ + (t + 1)) * D_ + upair * 8];
                xr0 = *(const float4*)xsrc;
                xr1 = *(const float4*)(xsrc + 4);
            }
            *(uint4v*)&hS[row * 520 + pr * 2]     = ra;
            *(uint4v*)&hS[row * 520 + pr * 2 + 8] = rb;
        }
        lds_barrier();   // D

        // ---- E: gate GEMMs + activations ----
        f32x4 accA0 = {bias0, bias0, bias0, bias0};
        f32x4 accA1 = {bias1, bias1, bias1, bias1};
        f32x4 accB0 = {0.f, 0.f, 0.f, 0.f};
        f32x4 accB1 = {0.f, 0.f, 0.f, 0.f};
        #pragma unroll
        for (int ks = 0; ks < 8; ++ks) {
            bf16x8 a = *(const bf16x8*)&xS[m * 264 + ks * 32 + q * 8];
            accA0 = __builtin_amdgcn_mfma_f32_16x16x32_bf16(a, WF[0][ks], accA0, 0, 0, 0);
            accA1 = __builtin_amdgcn_mfma_f32_16x16x32_bf16(a, WF[1][ks], accA1, 0, 0, 0);
        }
        #pragma unroll
        for (int ks = 0; ks < 16; ++ks) {
            bf16x8 a = *(const bf16x8*)&hS[m * 520 + ks * 32 + q * 8];
            accB0 = __builtin_amdgcn_mfma_f32_16x16x32_bf16(a, UF[0][ks], accB0, 0, 0, 0);
            accB1 = __builtin_amdgcn_mfma_f32_16x16x32_bf16(a, UF[1][ks], accB1, 0, 0, 0);
        }
        #pragma unroll
        for (int j = 0; j < 4; ++j) {
            float v0 = accA0[j] + accB0[j];
            float v1 = accA1[j] + accB1[j];
            v0 = (gate < 3) ? sigmoid_f(v0) : tanh_f(v0);
            v1 = (gate < 3) ? sigmoid_f(v1) : tanh_f(v1);
            gact[gate][q * 4 + j][half * 32 + m]      = v0;
            gact[gate][q * 4 + j][half * 32 + 16 + m] = v1;
        }
        lds_barrier();   // F

        // ---- G: update; ONE write-through {tag|data} store, fire-and-forget ----
        float2 f2v = *(const float2*)&gact[0][urow][2 * upair];
        float2 i2v = *(const float2*)&gact[1][urow][2 * upair];
        float2 o2v = *(const float2*)&gact[2][urow][2 * upair];
        float2 ch2 = *(const float2*)&gact[3][urow][2 * upair];
        cr0 = f2v.x * cr0 + i2v.x * ch2.x;
        cr1 = f2v.y * cr1 + i2v.y * ch2.y;
        float hv0 = o2v.x * tanh_f(cr0);
        float hv1 = o2v.y * tanh_f(cr1);

        if (t < S_ - 1) {
            unsigned int packed = (unsigned int)f2bf(hv0) | ((unsigned int)f2bf(hv1) << 16);
            u64_t ent = ((u64_t)(unsigned int)(t + 1) << 32) | (u64_t)packed;
            u64_t* hdst = hbuf + ((size_t)(((t + 1) & 1) * B_ + g * 16 + urow) * 256
                                  + s * 32 + upair);
            // sc0 sc1 write-through: local-L2 update + L3 forward. No drain.
            asm volatile("global_store_dwordx2 %0, %1, off sc0 sc1"
                         :: "v"(hdst), "v"(ent) : "memory");
            // xS(t+1): the f2bf VALU work + xr wait overlap the in-flight store
            bf16x8 v;
            v[0] = (short)f2bf(xr0.x); v[1] = (short)f2bf(xr0.y);
            v[2] = (short)f2bf(xr0.z); v[3] = (short)f2bf(xr0.w);
            v[4] = (short)f2bf(xr1.x); v[5] = (short)f2bf(xr1.y);
            v[6] = (short)f2bf(xr1.z); v[7] = (short)f2bf(xr1.w);
            *(bf16x8*)&xS[urow * 264 + upair * 8] = v;
        } else {
            *(float2*)&outH[(g * 16 + urow) * H_ + s * 64 + 2 * upair] = make_float2(hv0, hv1);
            *(float2*)&outC[(g * 16 + urow) * H_ + s * 64 + 2 * upair] = make_float2(cr0, cr1);
        }

        // ---- pred head (off the inter-block critical path) ----
        float pv = hv0 * wfc2.x + hv1 * wfc2.y;
        pv += __shfl_xor(pv, 16);
        pv += __shfl_xor(pv, 8);
        pv += __shfl_xor(pv, 4);
        pv += __shfl_xor(pv, 2);
        pv += __shfl_xor(pv, 1);
        if (upair == 0) atomicAdd(&pred[(g * 16 + urow) * S_ + t], pv);
    }
}

__global__ void pred_fin(const float* __restrict__ pred,
                         const float* __restrict__ bfc,
                         float* __restrict__ out)
{
    int i = blockIdx.x * blockDim.x + threadIdx.x;
    if (i < B_ * S_) out[i] = pred[i] + bfc[0];
}

extern "C" void kernel_launch(void* const* d_in, const int* in_sizes, int n_in,
                              void* d_out, int out_size, void* d_ws, size_t ws_size,
                              hipStream_t stream) {
    const float* X   = (const float*)d_in[0];
    const float* Wf  = (const float*)d_in[1];
    const float* Wi  = (const float*)d_in[2];
    const float* Wo  = (const float*)d_in[3];
    const float* Wc  = (const float*)d_in[4];
    const float* bfp = (const float*)d_in[5];
    const float* bip = (const float*)d_in[6];
    const float* bop = (const float*)d_in[7];
    const float* bcp = (const float*)d_in[8];
    const float* Uf  = (const float*)d_in[9];
    const float* Ui  = (const float*)d_in[10];
    const float* Uo  = (const float*)d_in[11];
    const float* Uc  = (const float*)d_in[12];
    const float* Wfc = (const float*)d_in[13];
    const float* bfc = (const float*)d_in[14];

    // ws layout: pred fp32 [64][512] @0 (128KB)
    //            | hbuf u64 [2][64][256] @131072 (256KB)
    //            | xcdtab @393216 (256B)
    float*        pred   = (float*)d_ws;
    u64_t*        hbuf   = (u64_t*)((char*)d_ws + 131072);
    unsigned int* xcdtab = (unsigned int*)((char*)d_ws + 393216);

    hipMemsetAsync(d_ws, 0, 393216 + 256, stream);   // pred, hbuf (tags=0), xcdtab

    float* out = (float*)d_out;
    lstm_rec<<<64, 512, 0, stream>>>(X, Wf, Wi, Wo, Wc, bfp, bip, bop, bcp,
                                     Uf, Ui, Uo, Uc, Wfc,
                                     pred, hbuf, xcdtab,
                                     out + 32768, out + 65536);
    pred_fin<<<128, 256, 0, stream>>>(pred, bfc, out);
}